// Round 1
// baseline (136.749 us; speedup 1.0000x reference)
//
#include <hip/hip_runtime.h>

#define NSLOTS 131072
#define NMASK  (NSLOTS-1)
#define NBATCH 256
#define DMEM   64
#define DIN    256
#define DCOMB  71
#define SPB    64                 // slots per block
#define NBLK   (NSLOTS/SPB)       // 2048
#define EPSF   1e-8f

typedef unsigned int   u32;
typedef unsigned short u16;
typedef __bf16 bf16x8 __attribute__((ext_vector_type(8)));
typedef float  f32x4  __attribute__((ext_vector_type(4)));

__device__ __forceinline__ u16 f2bf(float f) {
  u32 u = __builtin_bit_cast(u32, f);
  u += 0x7fffu + ((u >> 16) & 1u);          // RNE
  return (u16)(u >> 16);
}
__device__ __forceinline__ float bf2f(u16 v) {
  return __builtin_bit_cast(float, ((u32)v) << 16);
}
__device__ __forceinline__ u32 pk2(float a, float b) {
  return (u32)f2bf(a) | ((u32)f2bf(b) << 16);
}
__device__ __forceinline__ float blo(u32 u){ return __builtin_bit_cast(float, u << 16); }
__device__ __forceinline__ float bhi(u32 u){ return __builtin_bit_cast(float, u & 0xffff0000u); }

// ---------------- kernel 1: combined GEMM + per-batch params ----------------
__global__ __launch_bounds__(128) void ntm_prep(
    const float* __restrict__ inp, const float* __restrict__ W,
    const float* __restrict__ bias, u16* __restrict__ keysbf,
    float* __restrict__ params)
{
  __shared__ float comb[DCOMB];
  const int b = blockIdx.x;
  const int t = threadIdx.x;
  if (t < DCOMB) {
    float acc = bias[t];
    const float* ip = inp + (size_t)b * DIN;
    for (int i = 0; i < DIN; ++i) acc = fmaf(ip[i], W[i*DCOMB + t], acc);
    comb[t] = acc;
  }
  __syncthreads();
  if (t < 64) {
    float k = comb[t];
    keysbf[b*64 + t] = f2bf(k);
    float sq = k * k;
#pragma unroll
    for (int d = 1; d < 64; d <<= 1) sq += __shfl_xor(sq, d, 64);
    if (t == 0) {
      params[b*8+0] = sqrtf(sq);                       // key_norm (fp32 keys)
      params[b*8+1] = comb[64];                        // key_strength
      params[b*8+2] = 1.f/(1.f + __expf(-comb[65]));   // gate
      float c0 = comb[66], c1 = comb[67], c2 = comb[68];
      float mx = fmaxf(c0, fmaxf(c1, c2));
      float e0 = __expf(c0-mx), e1 = __expf(c1-mx), e2 = __expf(c2-mx);
      float inv = 1.f/(e0+e1+e2);
      params[b*8+3] = e0*inv; params[b*8+4] = e1*inv; params[b*8+5] = e2*inv;
    }
  }
}

// ---------------- kernel 2: per-block softmax stats (max, sumexp) ----------------
__global__ __launch_bounds__(512) void ntm_stats(
    const u16* __restrict__ keysbf, const float* __restrict__ memory,
    const float* __restrict__ params,
    float* __restrict__ maxpart, float* __restrict__ sumpart)
{
  __shared__ __align__(16) u16 keyl[NBATCH*DMEM];   // 32 KB, swizzled
  __shared__ __align__(16) u16 meml[SPB*DMEM];      // 8 KB, swizzled
  __shared__ float memnorm[SPB];
  const int t  = threadIdx.x;
  const int s0 = blockIdx.x * SPB;

  { // keys -> LDS (16B chunks, XOR swizzle on 8-elem blocks)
    const uint4* src = (const uint4*)keysbf;
#pragma unroll
    for (int j = 0; j < 4; ++j) {
      int q = t*4 + j;
      int r = q >> 3, cb = q & 7;
      uint4 v = src[q];
      *(uint4*)&keyl[r*DMEM + ((cb ^ (r & 7)) << 3)] = v;
    }
  }
  { // memory chunk -> bf16 LDS + fp32 row norms
    int r = t >> 3, c8 = t & 7;
    const float* mp = memory + (size_t)(s0 + r) * DMEM + c8 * 8;
    float4 f0 = *(const float4*)mp;
    float4 f1 = *(const float4*)(mp + 4);
    uint4 v;
    v.x = pk2(f0.x, f0.y); v.y = pk2(f0.z, f0.w);
    v.z = pk2(f1.x, f1.y); v.w = pk2(f1.z, f1.w);
    *(uint4*)&meml[r*DMEM + ((c8 ^ (r & 7)) << 3)] = v;
    float sq = f0.x*f0.x + f0.y*f0.y + f0.z*f0.z + f0.w*f0.w
             + f1.x*f1.x + f1.y*f1.y + f1.z*f1.z + f1.w*f1.w;
    sq += __shfl_xor(sq, 1, 64);
    sq += __shfl_xor(sq, 2, 64);
    sq += __shfl_xor(sq, 4, 64);
    if (c8 == 0) memnorm[r] = sqrtf(sq);
  }
  __syncthreads();

  const int w = t >> 6, L = t & 63;
  const int li = L & 15, hi4 = L >> 4;
  const int bc0 = w * 32;
  f32x4 zero = {0.f, 0.f, 0.f, 0.f};
  f32x4 acc[2][4];
#pragma unroll
  for (int ct = 0; ct < 2; ++ct)
#pragma unroll
    for (int rt = 0; rt < 4; ++rt) acc[ct][rt] = zero;

#pragma unroll
  for (int ks = 0; ks < 2; ++ks) {
    int cb = ks*4 + hi4;
    bf16x8 af[4], bfr[2];
#pragma unroll
    for (int rt = 0; rt < 4; ++rt) {
      int r = rt*16 + li;
      af[rt] = __builtin_bit_cast(bf16x8, *(const uint4*)&meml[r*DMEM + ((cb ^ (r&7)) << 3)]);
    }
#pragma unroll
    for (int ct = 0; ct < 2; ++ct) {
      int bb = bc0 + ct*16 + li;
      bfr[ct] = __builtin_bit_cast(bf16x8, *(const uint4*)&keyl[bb*DMEM + ((cb ^ (bb&7)) << 3)]);
    }
#pragma unroll
    for (int ct = 0; ct < 2; ++ct)
#pragma unroll
      for (int rt = 0; rt < 4; ++rt)
        acc[ct][rt] = __builtin_amdgcn_mfma_f32_16x16x32_bf16(af[rt], bfr[ct], acc[ct][rt], 0, 0, 0);
  }

#pragma unroll
  for (int ct = 0; ct < 2; ++ct) {
    int bb = bc0 + ct*16 + li;
    float kn    = params[bb*8 + 0];
    float alpha = params[bb*8 + 1];
    float lv[16];
#pragma unroll
    for (int rt = 0; rt < 4; ++rt)
#pragma unroll
      for (int r = 0; r < 4; ++r) {
        int sl = rt*16 + hi4*4 + r;
        lv[rt*4+r] = acc[ct][rt][r] * alpha / (kn * memnorm[sl] + EPSF);
      }
    float m = lv[0];
#pragma unroll
    for (int i = 1; i < 16; ++i) m = fmaxf(m, lv[i]);
    m = fmaxf(m, __shfl_xor(m, 16, 64));
    m = fmaxf(m, __shfl_xor(m, 32, 64));
    float s = 0.f;
#pragma unroll
    for (int i = 0; i < 16; ++i) s += __expf(lv[i] - m);
    s += __shfl_xor(s, 16, 64);
    s += __shfl_xor(s, 32, 64);
    if (hi4 == 0) {
      maxpart[(size_t)bb*NBLK + blockIdx.x] = m;
      sumpart[(size_t)bb*NBLK + blockIdx.x] = s;
    }
  }
}

// ---------------- kernel 3: global M, S per batch ----------------
__global__ __launch_bounds__(256) void ntm_reduce(
    const float* __restrict__ maxpart, const float* __restrict__ sumpart,
    float* __restrict__ Mv, float* __restrict__ Sv)
{
  __shared__ float red[8];
  const int b = blockIdx.x, t = threadIdx.x;
  const int w = t >> 6, L = t & 63;
  float m = -1e30f;
  for (int i = t; i < NBLK; i += 256) m = fmaxf(m, maxpart[(size_t)b*NBLK + i]);
#pragma unroll
  for (int d = 1; d < 64; d <<= 1) m = fmaxf(m, __shfl_xor(m, d, 64));
  if (L == 0) red[w] = m;
  __syncthreads();
  m = fmaxf(fmaxf(red[0], red[1]), fmaxf(red[2], red[3]));
  float s = 0.f;
  for (int i = t; i < NBLK; i += 256)
    s += sumpart[(size_t)b*NBLK + i] * __expf(maxpart[(size_t)b*NBLK + i] - m);
#pragma unroll
  for (int d = 1; d < 64; d <<= 1) s += __shfl_xor(s, d, 64);
  if (L == 0) red[4 + w] = s;
  __syncthreads();
  if (t == 0) { Mv[b] = m; Sv[b] = red[4] + red[5] + red[6] + red[7]; }
}

// ---------------- kernel 4: recompute dots -> w_c -> gate blend -> conv -> out ----------------
__global__ __launch_bounds__(512) void ntm_final(
    const u16* __restrict__ keysbf, const float* __restrict__ memory,
    const float* __restrict__ params, const float* __restrict__ Mv,
    const float* __restrict__ Sv, const float* __restrict__ prev,
    float* __restrict__ out)
{
  // pool: holds keys (phase 1) then re-used for staged wg' bf16 (phase 2)
  __shared__ __align__(16) u16 pool[NBATCH*DMEM];   // 32 KB
  __shared__ __align__(16) u16 meml[SPB*DMEM];      // 8 KB
  __shared__ __align__(16) u16 halom[2*DMEM];
  __shared__ float memnorm[SPB];
  __shared__ float halonorm[2];
  __shared__ u16 hlo[NBATCH], hhi[NBATCH];
  const int t  = threadIdx.x;
  const int s0 = blockIdx.x * SPB;

  { // keys -> LDS
    const uint4* src = (const uint4*)keysbf;
#pragma unroll
    for (int j = 0; j < 4; ++j) {
      int q = t*4 + j;
      int r = q >> 3, cb = q & 7;
      uint4 v = src[q];
      *(uint4*)&pool[r*DMEM + ((cb ^ (r & 7)) << 3)] = v;
    }
  }
  { // memory chunk -> bf16 LDS + norms
    int r = t >> 3, c8 = t & 7;
    const float* mp = memory + (size_t)(s0 + r) * DMEM + c8 * 8;
    float4 f0 = *(const float4*)mp;
    float4 f1 = *(const float4*)(mp + 4);
    uint4 v;
    v.x = pk2(f0.x, f0.y); v.y = pk2(f0.z, f0.w);
    v.z = pk2(f1.x, f1.y); v.w = pk2(f1.z, f1.w);
    *(uint4*)&meml[r*DMEM + ((c8 ^ (r & 7)) << 3)] = v;
    float sq = f0.x*f0.x + f0.y*f0.y + f0.z*f0.z + f0.w*f0.w
             + f1.x*f1.x + f1.y*f1.y + f1.z*f1.z + f1.w*f1.w;
    sq += __shfl_xor(sq, 1, 64);
    sq += __shfl_xor(sq, 2, 64);
    sq += __shfl_xor(sq, 4, 64);
    if (c8 == 0) memnorm[r] = sqrtf(sq);
  }
  if (t < 128) { // halo memory rows (slots s0-1 and s0+64, circular)
    int h = t >> 6, m = t & 63;
    int gs = (s0 + (h ? SPB : -1)) & NMASK;
    float v = memory[(size_t)gs * DMEM + m];
    halom[h*DMEM + m] = f2bf(v);
    float sq = v * v;
#pragma unroll
    for (int d = 1; d < 64; d <<= 1) sq += __shfl_xor(sq, d, 64);
    if (m == 0) halonorm[h] = sqrtf(sq);
  }
  __syncthreads();

  const int w = t >> 6, L = t & 63;
  const int li = L & 15, hi4 = L >> 4;
  const int bc0 = w * 32;
  f32x4 zero = {0.f, 0.f, 0.f, 0.f};
  f32x4 acc[2][4];
#pragma unroll
  for (int ct = 0; ct < 2; ++ct)
#pragma unroll
    for (int rt = 0; rt < 4; ++rt) acc[ct][rt] = zero;

#pragma unroll
  for (int ks = 0; ks < 2; ++ks) {
    int cb = ks*4 + hi4;
    bf16x8 af[4], bfr[2];
#pragma unroll
    for (int rt = 0; rt < 4; ++rt) {
      int r = rt*16 + li;
      af[rt] = __builtin_bit_cast(bf16x8, *(const uint4*)&meml[r*DMEM + ((cb ^ (r&7)) << 3)]);
    }
#pragma unroll
    for (int ct = 0; ct < 2; ++ct) {
      int bb = bc0 + ct*16 + li;
      bfr[ct] = __builtin_bit_cast(bf16x8, *(const uint4*)&pool[bb*DMEM + ((cb ^ (bb&7)) << 3)]);
    }
#pragma unroll
    for (int ct = 0; ct < 2; ++ct)
#pragma unroll
      for (int rt = 0; rt < 4; ++rt)
        acc[ct][rt] = __builtin_amdgcn_mfma_f32_16x16x32_bf16(af[rt], bfr[ct], acc[ct][rt], 0, 0, 0);
  }

  // halo wg' (VALU dot, reads keys from pool) -- last reader of keys
  u16 haloval; int halob, haloh;
  {
    int bb = t & 255, h = t >> 8;
    halob = bb; haloh = h;
    float dot = 0.f;
#pragma unroll
    for (int mb = 0; mb < 8; ++mb) {
      uint4 kv = *(const uint4*)&pool[bb*DMEM + ((mb ^ (bb & 7)) << 3)];
      uint4 mv = *(const uint4*)&halom[h*DMEM + mb*8];
      dot += blo(kv.x)*blo(mv.x) + bhi(kv.x)*bhi(mv.x);
      dot += blo(kv.y)*blo(mv.y) + bhi(kv.y)*bhi(mv.y);
      dot += blo(kv.z)*blo(mv.z) + bhi(kv.z)*bhi(mv.z);
      dot += blo(kv.w)*blo(mv.w) + bhi(kv.w)*bhi(mv.w);
    }
    float kn = params[bb*8+0], alpha = params[bb*8+1], g = params[bb*8+2];
    float l = dot * alpha / (kn * halonorm[h] + EPSF);
    haloval = f2bf(__expf(l - Mv[bb]) * g / Sv[bb]);
  }
  __syncthreads();   // keys fully consumed; pool can be re-used for wg'

  if (haloh) hhi[halob] = haloval; else hlo[halob] = haloval;

  // wg' = gate * softmax weight, staged bf16 into pool (swizzled 8B blocks)
#pragma unroll
  for (int ct = 0; ct < 2; ++ct) {
    int bb = bc0 + ct*16 + li;
    float kn = params[bb*8+0], alpha = params[bb*8+1], g = params[bb*8+2];
    float Mb = Mv[bb];
    float wfac = g / Sv[bb];
#pragma unroll
    for (int rt = 0; rt < 4; ++rt) {
      int sbase = rt*16 + hi4*4;
      float wv[4];
#pragma unroll
      for (int r = 0; r < 4; ++r) {
        int sl = sbase + r;
        float l = acc[ct][rt][r] * alpha / (kn * memnorm[sl] + EPSF);
        wv[r] = __expf(l - Mb) * wfac;
      }
      uint2 pkd;
      pkd.x = pk2(wv[0], wv[1]);
      pkd.y = pk2(wv[2], wv[3]);
      *(uint2*)&pool[bb*DMEM + (((sbase >> 2) ^ (bb & 15)) << 2)] = pkd;
    }
  }
  __syncthreads();

  // conv + output: out[b][s] = sum_k ck[k] * (wg'(s-1+k) + (1-g)*prev[b][s-1+k])
  {
    const int tb = t >> 3;
    const int so = (t & 7) * 8;
#pragma unroll
    for (int p = 0; p < 4; ++p) {
      int bb = p*64 + tb;
      float g  = params[bb*8+2];
      float c0 = params[bb*8+3], c1 = params[bb*8+4], c2 = params[bb*8+5];
      float og = 1.f - g;
      const float* pv = prev + (size_t)bb * NSLOTS;
      float wf[10];
#pragma unroll
      for (int i = 0; i < 10; ++i) {
        int sl = so - 1 + i;
        float pr = pv[(s0 + sl) & NMASK];
        float wq;
        if (sl < 0)          wq = bf2f(hlo[bb]);
        else if (sl >= SPB)  wq = bf2f(hhi[bb]);
        else                 wq = bf2f(pool[bb*DMEM + (((sl >> 2) ^ (bb & 15)) << 2) + (sl & 3)]);
        wf[i] = fmaf(og, pr, wq);
      }
      float4 o0, o1;
      o0.x = c0*wf[0] + c1*wf[1] + c2*wf[2];
      o0.y = c0*wf[1] + c1*wf[2] + c2*wf[3];
      o0.z = c0*wf[2] + c1*wf[3] + c2*wf[4];
      o0.w = c0*wf[3] + c1*wf[4] + c2*wf[5];
      o1.x = c0*wf[4] + c1*wf[5] + c2*wf[6];
      o1.y = c0*wf[5] + c1*wf[6] + c2*wf[7];
      o1.z = c0*wf[6] + c1*wf[7] + c2*wf[8];
      o1.w = c0*wf[7] + c1*wf[8] + c2*wf[9];
      float4* op = (float4*)(out + (size_t)bb * NSLOTS + s0 + so);
      op[0] = o0; op[1] = o1;
    }
  }
}

extern "C" void kernel_launch(void* const* d_in, const int* in_sizes, int n_in,
                              void* d_out, int out_size, void* d_ws, size_t ws_size,
                              hipStream_t stream)
{
  (void)in_sizes; (void)n_in; (void)out_size;
  const float* inp    = (const float*)d_in[0];
  const float* memory = (const float*)d_in[1];
  const float* prev   = (const float*)d_in[2];
  const float* W      = (const float*)d_in[3];
  const float* bias   = (const float*)d_in[4];
  float* out = (float*)d_out;
  char*  ws  = (char*)d_ws;

  u16*   keysbf = (u16*)ws;                    // 32 KB
  float* params = (float*)(ws + 32768);        // 8 KB: {kn, ks, g, ck0, ck1, ck2, -, -}
  float* Mv     = (float*)(ws + 40960);        // 1 KB
  float* Sv     = (float*)(ws + 41984);        // 1 KB
  float* maxpart;
  float* sumpart;
  const size_t partbytes = (size_t)NBATCH * NBLK * 4u;
  if (ws_size >= 49152 + 2*partbytes) {
    maxpart = (float*)(ws + 49152);
    sumpart = (float*)(ws + 49152 + partbytes);
  } else {
    // fall back to scratch inside d_out (fully overwritten by ntm_final afterwards)
    maxpart = out;
    sumpart = out + (size_t)NBATCH * NBLK;
  }

  hipLaunchKernelGGL(ntm_prep,   dim3(NBATCH), dim3(128), 0, stream, inp, W, bias, keysbf, params);
  hipLaunchKernelGGL(ntm_stats,  dim3(NBLK),   dim3(512), 0, stream, keysbf, memory, params, maxpart, sumpart);
  hipLaunchKernelGGL(ntm_reduce, dim3(NBATCH), dim3(256), 0, stream, maxpart, sumpart, Mv, Sv);
  hipLaunchKernelGGL(ntm_final,  dim3(NBLK),   dim3(512), 0, stream, keysbf, memory, params, Mv, Sv, prev, out);
}

// Round 2
// 132.353 us; speedup vs baseline: 1.0332x; 1.0332x over previous
//
#include <hip/hip_runtime.h>

#define NSLOTS 131072
#define NMASK  (NSLOTS-1)
#define NBATCH 256
#define DMEM   64
#define DIN    256
#define DCOMB  71
#define SPB    64                 // slots per block
#define NBLK   (NSLOTS/SPB)       // 2048
#define EPSF   1e-8f

typedef unsigned int   u32;
typedef unsigned short u16;
typedef __bf16 bf16x8 __attribute__((ext_vector_type(8)));
typedef float  f32x4  __attribute__((ext_vector_type(4)));

__device__ __forceinline__ u16 f2bf(float f) {
  u32 u = __builtin_bit_cast(u32, f);
  u += 0x7fffu + ((u >> 16) & 1u);          // RNE
  return (u16)(u >> 16);
}
__device__ __forceinline__ float bf2f(u16 v) {
  return __builtin_bit_cast(float, ((u32)v) << 16);
}
__device__ __forceinline__ u32 pk2(float a, float b) {
  return (u32)f2bf(a) | ((u32)f2bf(b) << 16);
}
__device__ __forceinline__ float blo(u32 u){ return __builtin_bit_cast(float, u << 16); }
__device__ __forceinline__ float bhi(u32 u){ return __builtin_bit_cast(float, u & 0xffff0000u); }

// ---------------- kernel 1: combined GEMM + per-batch params ----------------
__global__ __launch_bounds__(128) void ntm_prep(
    const float* __restrict__ inp, const float* __restrict__ W,
    const float* __restrict__ bias, u16* __restrict__ keysbf,
    float* __restrict__ params)
{
  __shared__ float comb[DCOMB];
  const int b = blockIdx.x;
  const int t = threadIdx.x;
  if (t < DCOMB) {
    float acc = bias[t];
    const float* ip = inp + (size_t)b * DIN;
    for (int i = 0; i < DIN; ++i) acc = fmaf(ip[i], W[i*DCOMB + t], acc);
    comb[t] = acc;
  }
  __syncthreads();
  if (t < 64) {
    float k = comb[t];
    keysbf[b*64 + t] = f2bf(k);
    float sq = k * k;
#pragma unroll
    for (int d = 1; d < 64; d <<= 1) sq += __shfl_xor(sq, d, 64);
    if (t == 0) {
      params[b*8+0] = sqrtf(sq);                       // key_norm (fp32 keys)
      params[b*8+1] = comb[64];                        // key_strength
      params[b*8+2] = 1.f/(1.f + __expf(-comb[65]));   // gate
      float c0 = comb[66], c1 = comb[67], c2 = comb[68];
      float mx = fmaxf(c0, fmaxf(c1, c2));
      float e0 = __expf(c0-mx), e1 = __expf(c1-mx), e2 = __expf(c2-mx);
      float inv = 1.f/(e0+e1+e2);
      params[b*8+3] = e0*inv; params[b*8+4] = e1*inv; params[b*8+5] = e2*inv;
    }
  }
}

// ---------------- kernel 2: per-block softmax stats (max, sumexp) ----------------
__global__ __launch_bounds__(512) void ntm_stats(
    const u16* __restrict__ keysbf, const float* __restrict__ memory,
    const float* __restrict__ params,
    float* __restrict__ maxpart, float* __restrict__ sumpart)
{
  __shared__ __align__(16) u16 keyl[NBATCH*DMEM];   // 32 KB, swizzled
  __shared__ __align__(16) u16 meml[SPB*DMEM];      // 8 KB, swizzled
  __shared__ float memnorm[SPB];
  const int t  = threadIdx.x;
  const int s0 = blockIdx.x * SPB;

  { // keys -> LDS (16B chunks, XOR swizzle on 8-elem blocks)
    const uint4* src = (const uint4*)keysbf;
#pragma unroll
    for (int j = 0; j < 4; ++j) {
      int q = t*4 + j;
      int r = q >> 3, cb = q & 7;
      uint4 v = src[q];
      *(uint4*)&keyl[r*DMEM + ((cb ^ (r & 7)) << 3)] = v;
    }
  }
  { // memory chunk -> bf16 LDS + fp32 row norms
    int r = t >> 3, c8 = t & 7;
    const float* mp = memory + (size_t)(s0 + r) * DMEM + c8 * 8;
    float4 f0 = *(const float4*)mp;
    float4 f1 = *(const float4*)(mp + 4);
    uint4 v;
    v.x = pk2(f0.x, f0.y); v.y = pk2(f0.z, f0.w);
    v.z = pk2(f1.x, f1.y); v.w = pk2(f1.z, f1.w);
    *(uint4*)&meml[r*DMEM + ((c8 ^ (r & 7)) << 3)] = v;
    float sq = f0.x*f0.x + f0.y*f0.y + f0.z*f0.z + f0.w*f0.w
             + f1.x*f1.x + f1.y*f1.y + f1.z*f1.z + f1.w*f1.w;
    sq += __shfl_xor(sq, 1, 64);
    sq += __shfl_xor(sq, 2, 64);
    sq += __shfl_xor(sq, 4, 64);
    if (c8 == 0) memnorm[r] = sqrtf(sq);
  }
  __syncthreads();

  const int w = t >> 6, L = t & 63;
  const int li = L & 15, hi4 = L >> 4;
  const int bc0 = w * 32;
  f32x4 zero = {0.f, 0.f, 0.f, 0.f};
  f32x4 acc[2][4];
#pragma unroll
  for (int ct = 0; ct < 2; ++ct)
#pragma unroll
    for (int rt = 0; rt < 4; ++rt) acc[ct][rt] = zero;

#pragma unroll
  for (int ks = 0; ks < 2; ++ks) {
    int cb = ks*4 + hi4;
    bf16x8 af[4], bfr[2];
#pragma unroll
    for (int rt = 0; rt < 4; ++rt) {
      int r = rt*16 + li;
      af[rt] = __builtin_bit_cast(bf16x8, *(const uint4*)&meml[r*DMEM + ((cb ^ (r&7)) << 3)]);
    }
#pragma unroll
    for (int ct = 0; ct < 2; ++ct) {
      int bb = bc0 + ct*16 + li;
      bfr[ct] = __builtin_bit_cast(bf16x8, *(const uint4*)&keyl[bb*DMEM + ((cb ^ (bb&7)) << 3)]);
    }
#pragma unroll
    for (int ct = 0; ct < 2; ++ct)
#pragma unroll
      for (int rt = 0; rt < 4; ++rt)
        acc[ct][rt] = __builtin_amdgcn_mfma_f32_16x16x32_bf16(af[rt], bfr[ct], acc[ct][rt], 0, 0, 0);
  }

#pragma unroll
  for (int ct = 0; ct < 2; ++ct) {
    int bb = bc0 + ct*16 + li;
    float kn    = params[bb*8 + 0];
    float alpha = params[bb*8 + 1];
    float lv[16];
#pragma unroll
    for (int rt = 0; rt < 4; ++rt)
#pragma unroll
      for (int r = 0; r < 4; ++r) {
        int sl = rt*16 + hi4*4 + r;
        lv[rt*4+r] = acc[ct][rt][r] * alpha / (kn * memnorm[sl] + EPSF);
      }
    float m = lv[0];
#pragma unroll
    for (int i = 1; i < 16; ++i) m = fmaxf(m, lv[i]);
    m = fmaxf(m, __shfl_xor(m, 16, 64));
    m = fmaxf(m, __shfl_xor(m, 32, 64));
    float s = 0.f;
#pragma unroll
    for (int i = 0; i < 16; ++i) s += __expf(lv[i] - m);
    s += __shfl_xor(s, 16, 64);
    s += __shfl_xor(s, 32, 64);
    if (hi4 == 0) {
      maxpart[(size_t)bb*NBLK + blockIdx.x] = m;
      sumpart[(size_t)bb*NBLK + blockIdx.x] = s;
    }
  }
}

// ---------------- kernel 3: global M, S per batch ----------------
__global__ __launch_bounds__(256) void ntm_reduce(
    const float* __restrict__ maxpart, const float* __restrict__ sumpart,
    float* __restrict__ Mv, float* __restrict__ Sv)
{
  __shared__ float red[8];
  const int b = blockIdx.x, t = threadIdx.x;
  const int w = t >> 6, L = t & 63;
  float m = -1e30f;
  for (int i = t; i < NBLK; i += 256) m = fmaxf(m, maxpart[(size_t)b*NBLK + i]);
#pragma unroll
  for (int d = 1; d < 64; d <<= 1) m = fmaxf(m, __shfl_xor(m, d, 64));
  if (L == 0) red[w] = m;
  __syncthreads();
  m = fmaxf(fmaxf(red[0], red[1]), fmaxf(red[2], red[3]));
  float s = 0.f;
  for (int i = t; i < NBLK; i += 256)
    s += sumpart[(size_t)b*NBLK + i] * __expf(maxpart[(size_t)b*NBLK + i] - m);
#pragma unroll
  for (int d = 1; d < 64; d <<= 1) s += __shfl_xor(s, d, 64);
  if (L == 0) red[4 + w] = s;
  __syncthreads();
  if (t == 0) { Mv[b] = m; Sv[b] = red[4] + red[5] + red[6] + red[7]; }
}

// ---------------- kernel 4: recompute dots -> w_c -> gate blend -> conv -> out ----------------
__global__ __launch_bounds__(512) void ntm_final(
    const u16* __restrict__ keysbf, const float* __restrict__ memory,
    const float* __restrict__ params, const float* __restrict__ Mv,
    const float* __restrict__ Sv, const float* __restrict__ prev,
    float* __restrict__ out)
{
  // pool: holds keys (phase 1) then re-used for staged wg' bf16 (phase 2)
  __shared__ __align__(16) u16 pool[NBATCH*DMEM];   // 32 KB
  __shared__ __align__(16) u16 meml[SPB*DMEM];      // 8 KB
  __shared__ __align__(16) u16 halom[2*DMEM];
  __shared__ float memnorm[SPB];
  __shared__ float halonorm[2];
  __shared__ u16 hlo[NBATCH], hhi[NBATCH];
  const int t  = threadIdx.x;
  const int s0 = blockIdx.x * SPB;

  { // keys -> LDS
    const uint4* src = (const uint4*)keysbf;
#pragma unroll
    for (int j = 0; j < 4; ++j) {
      int q = t*4 + j;
      int r = q >> 3, cb = q & 7;
      uint4 v = src[q];
      *(uint4*)&pool[r*DMEM + ((cb ^ (r & 7)) << 3)] = v;
    }
  }
  { // memory chunk -> bf16 LDS + norms
    int r = t >> 3, c8 = t & 7;
    const float* mp = memory + (size_t)(s0 + r) * DMEM + c8 * 8;
    float4 f0 = *(const float4*)mp;
    float4 f1 = *(const float4*)(mp + 4);
    uint4 v;
    v.x = pk2(f0.x, f0.y); v.y = pk2(f0.z, f0.w);
    v.z = pk2(f1.x, f1.y); v.w = pk2(f1.z, f1.w);
    *(uint4*)&meml[r*DMEM + ((c8 ^ (r & 7)) << 3)] = v;
    float sq = f0.x*f0.x + f0.y*f0.y + f0.z*f0.z + f0.w*f0.w
             + f1.x*f1.x + f1.y*f1.y + f1.z*f1.z + f1.w*f1.w;
    sq += __shfl_xor(sq, 1, 64);
    sq += __shfl_xor(sq, 2, 64);
    sq += __shfl_xor(sq, 4, 64);
    if (c8 == 0) memnorm[r] = sqrtf(sq);
  }
  if (t < 128) { // halo memory rows (slots s0-1 and s0+64, circular)
    int h = t >> 6, m = t & 63;
    int gs = (s0 + (h ? SPB : -1)) & NMASK;
    float v = memory[(size_t)gs * DMEM + m];
    halom[h*DMEM + m] = f2bf(v);
    float sq = v * v;
#pragma unroll
    for (int d = 1; d < 64; d <<= 1) sq += __shfl_xor(sq, d, 64);
    if (m == 0) halonorm[h] = sqrtf(sq);
  }
  __syncthreads();

  const int w = t >> 6, L = t & 63;
  const int li = L & 15, hi4 = L >> 4;
  const int bc0 = w * 32;
  f32x4 zero = {0.f, 0.f, 0.f, 0.f};
  f32x4 acc[2][4];
#pragma unroll
  for (int ct = 0; ct < 2; ++ct)
#pragma unroll
    for (int rt = 0; rt < 4; ++rt) acc[ct][rt] = zero;

#pragma unroll
  for (int ks = 0; ks < 2; ++ks) {
    int cb = ks*4 + hi4;
    bf16x8 af[4], bfr[2];
#pragma unroll
    for (int rt = 0; rt < 4; ++rt) {
      int r = rt*16 + li;
      af[rt] = __builtin_bit_cast(bf16x8, *(const uint4*)&meml[r*DMEM + ((cb ^ (r&7)) << 3)]);
    }
#pragma unroll
    for (int ct = 0; ct < 2; ++ct) {
      int bb = bc0 + ct*16 + li;
      bfr[ct] = __builtin_bit_cast(bf16x8, *(const uint4*)&pool[bb*DMEM + ((cb ^ (bb&7)) << 3)]);
    }
#pragma unroll
    for (int ct = 0; ct < 2; ++ct)
#pragma unroll
      for (int rt = 0; rt < 4; ++rt)
        acc[ct][rt] = __builtin_amdgcn_mfma_f32_16x16x32_bf16(af[rt], bfr[ct], acc[ct][rt], 0, 0, 0);
  }

  // halo wg' (VALU dot, reads keys from pool) -- last reader of keys
  u16 haloval; int halob, haloh;
  {
    int bb = t & 255, h = t >> 8;
    halob = bb; haloh = h;
    float dot = 0.f;
#pragma unroll
    for (int mb = 0; mb < 8; ++mb) {
      uint4 kv = *(const uint4*)&pool[bb*DMEM + ((mb ^ (bb & 7)) << 3)];
      uint4 mv = *(const uint4*)&halom[h*DMEM + mb*8];
      dot += blo(kv.x)*blo(mv.x) + bhi(kv.x)*bhi(mv.x);
      dot += blo(kv.y)*blo(mv.y) + bhi(kv.y)*bhi(mv.y);
      dot += blo(kv.z)*blo(mv.z) + bhi(kv.z)*bhi(mv.z);
      dot += blo(kv.w)*blo(mv.w) + bhi(kv.w)*bhi(mv.w);
    }
    float kn = params[bb*8+0], alpha = params[bb*8+1], g = params[bb*8+2];
    float l = dot * alpha / (kn * halonorm[h] + EPSF);
    haloval = f2bf(__expf(l - Mv[bb]) * g / Sv[bb]);
  }
  __syncthreads();   // keys fully consumed; pool can be re-used for wg'

  if (haloh) hhi[halob] = haloval; else hlo[halob] = haloval;

  // wg' = gate * softmax weight, staged bf16 into pool (swizzled 8B blocks)
#pragma unroll
  for (int ct = 0; ct < 2; ++ct) {
    int bb = bc0 + ct*16 + li;
    float kn = params[bb*8+0], alpha = params[bb*8+1], g = params[bb*8+2];
    float Mb = Mv[bb];
    float wfac = g / Sv[bb];
#pragma unroll
    for (int rt = 0; rt < 4; ++rt) {
      int sbase = rt*16 + hi4*4;
      float wv[4];
#pragma unroll
      for (int r = 0; r < 4; ++r) {
        int sl = sbase + r;
        float l = acc[ct][rt][r] * alpha / (kn * memnorm[sl] + EPSF);
        wv[r] = __expf(l - Mb) * wfac;
      }
      uint2 pkd;
      pkd.x = pk2(wv[0], wv[1]);
      pkd.y = pk2(wv[2], wv[3]);
      *(uint2*)&pool[bb*DMEM + (((sbase >> 2) ^ (bb & 15)) << 2)] = pkd;
    }
  }
  __syncthreads();

  // conv + output, fully-coalesced float4 loads/stores:
  // 16 lanes per batch row, 4 consecutive slots per lane, halo via shfl.
  {
    const int g  = t & 15;          // slot-group within row
    const int tb = t >> 4;          // 0..31: row within this pass
    const int so = g * 4;
#pragma unroll
    for (int p = 0; p < 8; ++p) {
      int bb = p*32 + tb;
      float gg = params[bb*8+2];
      float c0 = params[bb*8+3], c1 = params[bb*8+4], c2 = params[bb*8+5];
      float og = 1.f - gg;
      const float* pv = prev + (size_t)bb * NSLOTS;
      float4 pr = *(const float4*)(pv + s0 + so);
      uint2 wu = *(const uint2*)&pool[bb*DMEM + ((g ^ (bb & 15)) << 2)];
      float w0 = blo(wu.x), w1 = bhi(wu.x), w2 = blo(wu.y), w3 = bhi(wu.y);
      float lpr = __shfl_up(pr.w, 1, 64);
      float rpr = __shfl_down(pr.x, 1, 64);
      float lw  = __shfl_up(w3, 1, 64);
      float rw  = __shfl_down(w0, 1, 64);
      if (g == 0)  { lpr = pv[(s0 - 1) & NMASK];   lw = bf2f(hlo[bb]); }
      if (g == 15) { rpr = pv[(s0 + SPB) & NMASK]; rw = bf2f(hhi[bb]); }
      float fm1 = fmaf(og, lpr,  lw);
      float f0  = fmaf(og, pr.x, w0);
      float f1  = fmaf(og, pr.y, w1);
      float f2  = fmaf(og, pr.z, w2);
      float f3  = fmaf(og, pr.w, w3);
      float f4  = fmaf(og, rpr,  rw);
      float4 o;
      o.x = c0*fm1 + c1*f0 + c2*f1;
      o.y = c0*f0  + c1*f1 + c2*f2;
      o.z = c0*f1  + c1*f2 + c2*f3;
      o.w = c0*f2  + c1*f3 + c2*f4;
      *(float4*)(out + (size_t)bb * NSLOTS + s0 + so) = o;
    }
  }
}

extern "C" void kernel_launch(void* const* d_in, const int* in_sizes, int n_in,
                              void* d_out, int out_size, void* d_ws, size_t ws_size,
                              hipStream_t stream)
{
  (void)in_sizes; (void)n_in; (void)out_size;
  const float* inp    = (const float*)d_in[0];
  const float* memory = (const float*)d_in[1];
  const float* prev   = (const float*)d_in[2];
  const float* W      = (const float*)d_in[3];
  const float* bias   = (const float*)d_in[4];
  float* out = (float*)d_out;
  char*  ws  = (char*)d_ws;

  u16*   keysbf = (u16*)ws;                    // 32 KB
  float* params = (float*)(ws + 32768);        // 8 KB: {kn, ks, g, ck0, ck1, ck2, -, -}
  float* Mv     = (float*)(ws + 40960);        // 1 KB
  float* Sv     = (float*)(ws + 41984);        // 1 KB
  float* maxpart;
  float* sumpart;
  const size_t partbytes = (size_t)NBATCH * NBLK * 4u;
  if (ws_size >= 49152 + 2*partbytes) {
    maxpart = (float*)(ws + 49152);
    sumpart = (float*)(ws + 49152 + partbytes);
  } else {
    // fall back to scratch inside d_out (fully overwritten by ntm_final afterwards)
    maxpart = out;
    sumpart = out + (size_t)NBATCH * NBLK;
  }

  hipLaunchKernelGGL(ntm_prep,   dim3(NBATCH), dim3(128), 0, stream, inp, W, bias, keysbf, params);
  hipLaunchKernelGGL(ntm_stats,  dim3(NBLK),   dim3(512), 0, stream, keysbf, memory, params, maxpart, sumpart);
  hipLaunchKernelGGL(ntm_reduce, dim3(NBATCH), dim3(256), 0, stream, maxpart, sumpart, Mv, Sv);
  hipLaunchKernelGGL(ntm_final,  dim3(NBLK),   dim3(512), 0, stream, keysbf, memory, params, Mv, Sv, prev, out);
}

// Round 3
// 128.895 us; speedup vs baseline: 1.0609x; 1.0268x over previous
//
#include <hip/hip_runtime.h>

#define NSLOTS 131072
#define NMASK  (NSLOTS-1)
#define NBATCH 256
#define DMEM   64
#define DIN    256
#define DCOMB  71
#define SPB    64                 // slots per tile
#define NBLK   (NSLOTS/SPB)       // 2048
#define EPSF   1e-8f

typedef unsigned int   u32;
typedef unsigned short u16;
typedef __bf16 bf16x8 __attribute__((ext_vector_type(8)));
typedef float  f32x4  __attribute__((ext_vector_type(4)));

__device__ __forceinline__ u16 f2bf(float f) {
  u32 u = __builtin_bit_cast(u32, f);
  u += 0x7fffu + ((u >> 16) & 1u);          // RNE
  return (u16)(u >> 16);
}
__device__ __forceinline__ float bf2f(u16 v) {
  return __builtin_bit_cast(float, ((u32)v) << 16);
}
__device__ __forceinline__ u32 pk2(float a, float b) {
  return (u32)f2bf(a) | ((u32)f2bf(b) << 16);
}
__device__ __forceinline__ float blo(u32 u){ return __builtin_bit_cast(float, u << 16); }
__device__ __forceinline__ float bhi(u32 u){ return __builtin_bit_cast(float, u & 0xffff0000u); }

// ---------------- kernel 1: combined GEMM + per-batch params ----------------
// params[b*8]: {abk = ks/kn, C = |ks|, gate, ck0, ck1, ck2, -, -}
__global__ __launch_bounds__(128) void ntm_prep(
    const float* __restrict__ inp, const float* __restrict__ W,
    const float* __restrict__ bias, u16* __restrict__ keysbf,
    float* __restrict__ params)
{
  __shared__ float comb[DCOMB];
  const int b = blockIdx.x;
  const int t = threadIdx.x;
  if (t < DCOMB) {
    float acc = bias[t];
    const float* ip = inp + (size_t)b * DIN;
    for (int i = 0; i < DIN; ++i) acc = fmaf(ip[i], W[i*DCOMB + t], acc);
    comb[t] = acc;
  }
  __syncthreads();
  if (t < 64) {
    float k = comb[t];
    keysbf[b*64 + t] = f2bf(k);
    float sq = k * k;
#pragma unroll
    for (int d = 1; d < 64; d <<= 1) sq += __shfl_xor(sq, d, 64);
    if (t == 0) {
      float kn = sqrtf(sq);
      float ks = comb[64];
      params[b*8+0] = ks / kn;                         // abk
      params[b*8+1] = fabsf(ks);                       // softmax shift C (>= max logit)
      params[b*8+2] = 1.f/(1.f + __expf(-comb[65]));   // gate
      float c0 = comb[66], c1 = comb[67], c2 = comb[68];
      float mx = fmaxf(c0, fmaxf(c1, c2));
      float e0 = __expf(c0-mx), e1 = __expf(c1-mx), e2 = __expf(c2-mx);
      float inv = 1.f/(e0+e1+e2);
      params[b*8+3] = e0*inv; params[b*8+4] = e1*inv; params[b*8+5] = e2*inv;
    }
  }
}

// ---------------- kernel 2: per-(tile,half) sum of exp(l - C) ----------------
__global__ __launch_bounds__(512, 8) void ntm_stats(
    const u16* __restrict__ keysbf, const float* __restrict__ memory,
    const float* __restrict__ params, float* __restrict__ sumpart)
{
  __shared__ __align__(16) u16 meml[SPB*DMEM];      // 8 KB, swizzled
  __shared__ float invmn[SPB];
  const int t     = threadIdx.x;
  const int s0    = blockIdx.x * SPB;
  const int bbase = blockIdx.y * 128;

  { // memory tile -> bf16 LDS + 1/norm
    int r = t >> 3, c8 = t & 7;
    const float* mp = memory + (size_t)(s0 + r) * DMEM + c8 * 8;
    float4 f0 = *(const float4*)mp;
    float4 f1 = *(const float4*)(mp + 4);
    uint4 v;
    v.x = pk2(f0.x, f0.y); v.y = pk2(f0.z, f0.w);
    v.z = pk2(f1.x, f1.y); v.w = pk2(f1.z, f1.w);
    *(uint4*)&meml[r*DMEM + ((c8 ^ (r & 7)) << 3)] = v;
    float sq = f0.x*f0.x + f0.y*f0.y + f0.z*f0.z + f0.w*f0.w
             + f1.x*f1.x + f1.y*f1.y + f1.z*f1.z + f1.w*f1.w;
    sq += __shfl_xor(sq, 1, 64);
    sq += __shfl_xor(sq, 2, 64);
    sq += __shfl_xor(sq, 4, 64);
    if (c8 == 0) invmn[r] = rsqrtf(sq);
  }
  __syncthreads();

  const int w = t >> 6, L = t & 63;
  const int li = L & 15, hi4 = L >> 4;
  const int bb = bbase + w*16 + li;
  const uint4* kb = (const uint4*)(keysbf + (size_t)bb * DMEM);
  f32x4 zero = {0.f, 0.f, 0.f, 0.f};
  f32x4 acc[4];
#pragma unroll
  for (int rt = 0; rt < 4; ++rt) acc[rt] = zero;

#pragma unroll
  for (int ks = 0; ks < 2; ++ks) {
    int cb = ks*4 + hi4;
    bf16x8 bfr = __builtin_bit_cast(bf16x8, kb[cb]);
#pragma unroll
    for (int rt = 0; rt < 4; ++rt) {
      int r = rt*16 + li;
      bf16x8 af = __builtin_bit_cast(bf16x8, *(const uint4*)&meml[r*DMEM + ((cb ^ (r&7)) << 3)]);
      acc[rt] = __builtin_amdgcn_mfma_f32_16x16x32_bf16(af, bfr, acc[rt], 0, 0, 0);
    }
  }

  float abk = params[bb*8 + 0];
  float C   = params[bb*8 + 1];
  float s = 0.f;
#pragma unroll
  for (int rt = 0; rt < 4; ++rt)
#pragma unroll
    for (int r = 0; r < 4; ++r) {
      int sl = rt*16 + hi4*4 + r;
      s += __expf(acc[rt][r] * abk * invmn[sl] - C);
    }
  s += __shfl_xor(s, 16, 64);
  s += __shfl_xor(s, 32, 64);
  if (hi4 == 0) sumpart[(size_t)bb*NBLK + blockIdx.x] = s;
}

// ---------------- kernel 3: global S per batch ----------------
__global__ __launch_bounds__(256) void ntm_reduce(
    const float* __restrict__ sumpart, float* __restrict__ Sv)
{
  __shared__ float red[4];
  const int b = blockIdx.x, t = threadIdx.x;
  const int w = t >> 6, L = t & 63;
  float s = 0.f;
  for (int i = t; i < NBLK; i += 256) s += sumpart[(size_t)b*NBLK + i];
#pragma unroll
  for (int d = 1; d < 64; d <<= 1) s += __shfl_xor(s, d, 64);
  if (L == 0) red[w] = s;
  __syncthreads();
  if (t == 0) Sv[b] = red[0] + red[1] + red[2] + red[3];
}

// ---------------- kernel 4: recompute -> w_c -> gate blend -> conv -> out ----------------
__global__ __launch_bounds__(512, 8) void ntm_final(
    const u16* __restrict__ keysbf, const float* __restrict__ memory,
    const float* __restrict__ params, const float* __restrict__ Sv,
    const float* __restrict__ prev, float* __restrict__ out)
{
  __shared__ __align__(16) u16 pool[128*DMEM];      // 16 KB: wg' bf16, swizzled
  __shared__ __align__(16) u16 meml[SPB*DMEM];      // 8 KB, swizzled
  __shared__ __align__(16) u16 halom[2*DMEM];
  __shared__ float invmn[SPB];
  __shared__ float invhn[2];
  __shared__ u16 hlo[128], hhi[128];
  const int t     = threadIdx.x;
  const int s0    = blockIdx.x * SPB;
  const int bbase = blockIdx.y * 128;

  { // memory tile -> bf16 LDS + 1/norm
    int r = t >> 3, c8 = t & 7;
    const float* mp = memory + (size_t)(s0 + r) * DMEM + c8 * 8;
    float4 f0 = *(const float4*)mp;
    float4 f1 = *(const float4*)(mp + 4);
    uint4 v;
    v.x = pk2(f0.x, f0.y); v.y = pk2(f0.z, f0.w);
    v.z = pk2(f1.x, f1.y); v.w = pk2(f1.z, f1.w);
    *(uint4*)&meml[r*DMEM + ((c8 ^ (r & 7)) << 3)] = v;
    float sq = f0.x*f0.x + f0.y*f0.y + f0.z*f0.z + f0.w*f0.w
             + f1.x*f1.x + f1.y*f1.y + f1.z*f1.z + f1.w*f1.w;
    sq += __shfl_xor(sq, 1, 64);
    sq += __shfl_xor(sq, 2, 64);
    sq += __shfl_xor(sq, 4, 64);
    if (c8 == 0) invmn[r] = rsqrtf(sq);
  }
  if (t < 128) { // halo memory rows (slots s0-1, s0+64 circular)
    int h = t >> 6, m = t & 63;
    int gs = (s0 + (h ? SPB : -1)) & NMASK;
    float v = memory[(size_t)gs * DMEM + m];
    halom[h*DMEM + m] = f2bf(v);
    float sq = v * v;
#pragma unroll
    for (int d = 1; d < 64; d <<= 1) sq += __shfl_xor(sq, d, 64);
    if (m == 0) invhn[h] = rsqrtf(sq);
  }
  __syncthreads();

  const int w = t >> 6, L = t & 63;
  const int li = L & 15, hi4 = L >> 4;
  const int bb = bbase + w*16 + li;
  const int pb = w*16 + li;          // pool row (0..127)
  const uint4* kb = (const uint4*)(keysbf + (size_t)bb * DMEM);
  f32x4 zero = {0.f, 0.f, 0.f, 0.f};
  f32x4 acc[4];
#pragma unroll
  for (int rt = 0; rt < 4; ++rt) acc[rt] = zero;

#pragma unroll
  for (int ks = 0; ks < 2; ++ks) {
    int cb = ks*4 + hi4;
    bf16x8 bfr = __builtin_bit_cast(bf16x8, kb[cb]);
#pragma unroll
    for (int rt = 0; rt < 4; ++rt) {
      int r = rt*16 + li;
      bf16x8 af = __builtin_bit_cast(bf16x8, *(const uint4*)&meml[r*DMEM + ((cb ^ (r&7)) << 3)]);
      acc[rt] = __builtin_amdgcn_mfma_f32_16x16x32_bf16(af, bfr, acc[rt], 0, 0, 0);
    }
  }

  // halo wg' for this half's 128 batches (VALU dot, keys from L2)
  if (t < 256) {
    int hb = t & 127, hh = t >> 7;
    int gb = bbase + hb;
    const uint4* kb2 = (const uint4*)(keysbf + (size_t)gb * DMEM);
    float dot = 0.f;
#pragma unroll
    for (int mb = 0; mb < 8; ++mb) {
      uint4 kv = kb2[mb];
      uint4 mv = *(const uint4*)&halom[hh*DMEM + mb*8];
      dot += blo(kv.x)*blo(mv.x) + bhi(kv.x)*bhi(mv.x);
      dot += blo(kv.y)*blo(mv.y) + bhi(kv.y)*bhi(mv.y);
      dot += blo(kv.z)*blo(mv.z) + bhi(kv.z)*bhi(mv.z);
      dot += blo(kv.w)*blo(mv.w) + bhi(kv.w)*bhi(mv.w);
    }
    float abk = params[gb*8+0], C = params[gb*8+1], gg = params[gb*8+2];
    float l = dot * abk * invhn[hh];
    u16 hv = f2bf(__expf(l - C) * gg / Sv[gb]);
    if (hh) hhi[hb] = hv; else hlo[hb] = hv;
  }

  // wg' = gate * exp(l - C)/S, staged bf16 into pool (swizzled 8B chunks)
  {
    float abk = params[bb*8+0], C = params[bb*8+1], gg = params[bb*8+2];
    float wfac = gg / Sv[bb];
#pragma unroll
    for (int rt = 0; rt < 4; ++rt) {
      int sbase = rt*16 + hi4*4;
      float wv[4];
#pragma unroll
      for (int r = 0; r < 4; ++r) {
        int sl = sbase + r;
        wv[r] = __expf(acc[rt][r] * abk * invmn[sl] - C) * wfac;
      }
      uint2 pkd;
      pkd.x = pk2(wv[0], wv[1]);
      pkd.y = pk2(wv[2], wv[3]);
      *(uint2*)&pool[pb*DMEM + (((sbase >> 2) ^ (pb & 15)) << 2)] = pkd;
    }
  }
  __syncthreads();

  // conv + output: coalesced float4, 16 lanes/row, halo via shfl
  {
    const int g2 = t & 15;
    const int tb = t >> 4;           // 0..31
    const int so = g2 * 4;
#pragma unroll
    for (int p = 0; p < 4; ++p) {
      int pb2 = p*32 + tb;
      int bb2 = bbase + pb2;
      float gg = params[bb2*8+2];
      float c0 = params[bb2*8+3], c1 = params[bb2*8+4], c2 = params[bb2*8+5];
      float og = 1.f - gg;
      const float* pv = prev + (size_t)bb2 * NSLOTS;
      float4 pr = *(const float4*)(pv + s0 + so);
      uint2 wu = *(const uint2*)&pool[pb2*DMEM + ((g2 ^ (pb2 & 15)) << 2)];
      float w0 = blo(wu.x), w1 = bhi(wu.x), w2 = blo(wu.y), w3 = bhi(wu.y);
      float lpr = __shfl_up(pr.w, 1, 64);
      float rpr = __shfl_down(pr.x, 1, 64);
      float lw  = __shfl_up(w3, 1, 64);
      float rw  = __shfl_down(w0, 1, 64);
      if (g2 == 0)  { lpr = pv[(s0 - 1) & NMASK];   lw = bf2f(hlo[pb2]); }
      if (g2 == 15) { rpr = pv[(s0 + SPB) & NMASK]; rw = bf2f(hhi[pb2]); }
      float fm1 = fmaf(og, lpr,  lw);
      float f0  = fmaf(og, pr.x, w0);
      float f1  = fmaf(og, pr.y, w1);
      float f2  = fmaf(og, pr.z, w2);
      float f3  = fmaf(og, pr.w, w3);
      float f4  = fmaf(og, rpr,  rw);
      float4 o;
      o.x = c0*fm1 + c1*f0 + c2*f1;
      o.y = c0*f0  + c1*f1 + c2*f2;
      o.z = c0*f1  + c1*f2 + c2*f3;
      o.w = c0*f2  + c1*f3 + c2*f4;
      *(float4*)(out + (size_t)bb2 * NSLOTS + s0 + so) = o;
    }
  }
}

extern "C" void kernel_launch(void* const* d_in, const int* in_sizes, int n_in,
                              void* d_out, int out_size, void* d_ws, size_t ws_size,
                              hipStream_t stream)
{
  (void)in_sizes; (void)n_in; (void)out_size;
  const float* inp    = (const float*)d_in[0];
  const float* memory = (const float*)d_in[1];
  const float* prev   = (const float*)d_in[2];
  const float* W      = (const float*)d_in[3];
  const float* bias   = (const float*)d_in[4];
  float* out = (float*)d_out;
  char*  ws  = (char*)d_ws;

  u16*   keysbf = (u16*)ws;                    // 32 KB
  float* params = (float*)(ws + 32768);        // 8 KB
  float* Sv     = (float*)(ws + 40960);        // 1 KB
  float* sumpart;
  const size_t partbytes = (size_t)NBATCH * NBLK * 4u;
  if (ws_size >= 49152 + partbytes) {
    sumpart = (float*)(ws + 49152);
  } else {
    // scratch inside d_out (fully overwritten by ntm_final afterwards)
    sumpart = out;
  }

  hipLaunchKernelGGL(ntm_prep,   dim3(NBATCH),  dim3(128), 0, stream, inp, W, bias, keysbf, params);
  hipLaunchKernelGGL(ntm_stats,  dim3(NBLK, 2), dim3(512), 0, stream, keysbf, memory, params, sumpart);
  hipLaunchKernelGGL(ntm_reduce, dim3(NBATCH),  dim3(256), 0, stream, sumpart, Sv);
  hipLaunchKernelGGL(ntm_final,  dim3(NBLK, 2), dim3(512), 0, stream, keysbf, memory, params, Sv, prev, out);
}